// Round 19
// baseline (119.318 us; speedup 1.0000x reference)
//
#include <hip/hip_runtime.h>

#define N_NODES 50000
#define N_EDGES 800000
// D_S=64, D_R=16, D_E=64, D_X=16, D_P=64, NUM_CLASSES=10
// W_r: [144,64]; W_o: [144,64]; W_s: [64,10] (all row-major)
//
// Linear refactor: scores[n] = u0[n] + deg_n*u1[n] + sum_{e->n} w_e
//   w_e  = u_s[s_e] + R_a[e]@A_R          (computed in EDGE order, streamed)
//   u_s[n] = O[n]@A_S ; u0[n] = O[n]@A_O + X[n]@A_X + c1 ; u1[n] = O[n]@A_dO + c0
// with Wc = W_o@W_s [144,10], Wc2 = Wc[80:144],
//   A_O = Wc[0:64], A_X = Wc[64:80], A_S = W_r[0:64]@Wc2,
//   A_R = W_r[128:144]@Wc2, A_dO = W_r[64:128]@Wc2,
//   c0 = b_r@Wc2, c1 = b_o@W_s + b_s.
//
// r12: ILP does not help edge_w (scatter-store wall, ~52 us).
// r14: nt stores regressed (L2 RMW merge helps). r13: bins disaster.
// r17: software grid barrier = full L2 wb/inv per phase; reverted.
// r18: profile exposed count_rank's 800K device atomics as a SECOND ~52 us
//      wall (~15-18 G atomic/s, matches r0's 51.2M/2840us).
// r19 (this): XCD-PRIVATIZED histogram. 8 private count arrays indexed by
//      blockIdx%8 (round-robin XCD heuristic; correctness independent of
//      mapping). Atomic lines stay in one XCD's L2 -> no cross-XCD
//      migration. rank8[e] = private-atomic return (u8; max deg ~35).
//      alloc prefixes the 8 private counts per node in-place (goff), so
//      pos = off[r] + goff[g(e)][r] + rank8[e], g(e) = (e>>10)&7.
//
// A-table layout in ws: [226][16] f32 (cols 10..15 zeroed):
//   rows 0..63 A_O | 64..79 A_X | 80..143 A_S | 144..159 A_R |
//   160..223 A_dO | 224 c0 | 225 c1

// ---------------------------------------------------------------------------
// Workspace layout (bytes) — end = 25,228,288 < 26,414,400 (proven in r3)
// ---------------------------------------------------------------------------
#define WS_A       ((size_t)0)          // 14,464 B
#define WS_COUNT   ((size_t)16384)      // 50000 i32 (written by alloc, no memset)
#define WS_OFF     ((size_t)217088)     // 50000 i32
#define WS_RANK8   ((size_t)417792)     // 800000 u8 = 800,000 B
#define WS_CURSOR  ((size_t)1220544)    // 1 u32 (zeroed with cpriv memset)
#define WS_CPRIV   ((size_t)1220608)    // 8*50000 i32 = 1,600,000 B
#define WS_US      ((size_t)2824192)    // 50000*12 f32 = 2,400,000 B
#define WS_U01     ((size_t)5226496)    // 50000*20 f32 = 4,000,000 B
#define WS_WSORT   ((size_t)9228288)    // 800000*5 u32 = 16,000,000 B

#define NB_PRE   10                     // precompute_A blocks
#define NB_CR    ((N_EDGES / 4 + 255) / 256)        // 782 count blocks
#define NB_ALLOC ((N_NODES + 255) / 256)            // 196 alloc blocks
#define NB_NU    ((N_NODES * 5 + 255) / 256)        // 977 node_u blocks

__device__ __forceinline__ unsigned int f32_to_bf16_rne(float f) {
    unsigned int x = __float_as_uint(f);
    return (x + 0x7fffu + ((x >> 16) & 1u)) >> 16;
}

// ---------------------------------------------------------------------------
// Fused K1: blocks [0,NB_PRE) precompute A; blocks [NB_PRE,..) count+rank
// into the XCD-private histogram (blockIdx%8 selects the private array).
// ---------------------------------------------------------------------------
__global__ __launch_bounds__(256) void fused_prep_kernel(
    const float* __restrict__ W_r, const float* __restrict__ b_r,
    const float* __restrict__ W_o, const float* __restrict__ b_o,
    const float* __restrict__ W_s, const float* __restrict__ b_s,
    const int* __restrict__ receivers,
    float* __restrict__ A, int* __restrict__ cpriv,
    unsigned char* __restrict__ rank8)
{
    __shared__ float Wc2[640];  // used by precompute role only
    const int t = threadIdx.x;

    if (blockIdx.x < NB_PRE) {
        // ---- precompute_A role (grid-stride over NB_PRE blocks) ----
        for (int idx = t; idx < 640; idx += 256) {
            const int row = 80 + idx / 10, c = idx % 10;
            float acc = 0.f;
            for (int j = 0; j < 64; ++j)
                acc = fmaf(W_o[row * 64 + j], W_s[j * 10 + c], acc);
            Wc2[idx] = acc;
        }
        __syncthreads();

        for (int g = blockIdx.x * 256 + t; g < 3616; g += NB_PRE * 256) {
            if (g < 1356) {
                const int row = g / 6, c = 10 + g % 6;
                A[row * 16 + c] = 0.f;
            } else if (g < 2156) {
                const int i = g - 1356, row = i / 10, c = i % 10;
                float acc = 0.f;
                for (int j = 0; j < 64; ++j)
                    acc = fmaf(W_o[row * 64 + j], W_s[j * 10 + c], acc);
                A[row * 16 + c] = acc;
            } else if (g < 3596) {
                const int i = g - 2156, k = i / 10, c = i % 10;
                const int wrow = (k < 64) ? k : (k < 80 ? 128 + (k - 64) : 64 + (k - 80));
                const int arow = (k < 64) ? 80 + k : (k < 80 ? 144 + (k - 64) : 160 + (k - 80));
                const float* src = W_r + (size_t)wrow * 64;
                float acc = 0.f;
                for (int m = 0; m < 64; ++m)
                    acc = fmaf(src[m], Wc2[m * 10 + c], acc);
                A[arow * 16 + c] = acc;
            } else if (g < 3606) {
                const int c = g - 3596;
                float acc = 0.f;
                for (int m = 0; m < 64; ++m)
                    acc = fmaf(b_r[m], Wc2[m * 10 + c], acc);
                A[224 * 16 + c] = acc;
            } else {
                const int c = g - 3606;
                float acc = b_s[c];
                for (int j = 0; j < 64; ++j)
                    acc = fmaf(b_o[j], W_s[j * 10 + c], acc);
                A[225 * 16 + c] = acc;
            }
        }
    } else {
        // ---- count role: XCD-private histogram; atomic return = rank ----
        const int bt = blockIdx.x - NB_PRE;          // 0..NB_CR-1
        int* cp = cpriv + (size_t)(bt & 7) * N_NODES;
        const int t4 = bt * 256 + t;                 // int4 index
        if (t4 * 4 >= N_EDGES) return;
        const int4 r4 = reinterpret_cast<const int4*>(receivers)[t4];
        uchar4 k4;
        k4.x = (unsigned char)atomicAdd(cp + r4.x, 1);
        k4.y = (unsigned char)atomicAdd(cp + r4.y, 1);
        k4.z = (unsigned char)atomicAdd(cp + r4.z, 1);
        k4.w = (unsigned char)atomicAdd(cp + r4.w, 1);
        reinterpret_cast<uchar4*>(rank8)[t4] = k4;
    }
}

// ---------------------------------------------------------------------------
// Fused K2: blocks [0,NB_ALLOC) {combine private counts -> goff (in-place) +
// total count + segment alloc}; blocks [NB_ALLOC,..) node_u.
// ---------------------------------------------------------------------------
__global__ __launch_bounds__(256) void fused_mid_kernel(
    const float* __restrict__ O, const float* __restrict__ X,
    const float* __restrict__ A,
    int* __restrict__ cpriv, int* __restrict__ count,
    unsigned int* __restrict__ cursor, int* __restrict__ off,
    float* __restrict__ us, float* __restrict__ u01)
{
    __shared__ float2 lA[226 * 5];  // used by node_u role only
    const int t = threadIdx.x;

    if (blockIdx.x < NB_ALLOC) {
        // ---- combine + alloc role ----
        const int n = blockIdx.x * 256 + t;
        const int lane = t & 63;
        int c = 0;
        if (n < N_NODES) {
            int run = 0;
#pragma unroll
            for (int g = 0; g < 8; ++g) {
                const int v = cpriv[(size_t)g * N_NODES + n];
                cpriv[(size_t)g * N_NODES + n] = run;   // goff[g][n] in place
                run += v;
            }
            c = run;
            count[n] = c;                               // total degree
        }

        // wave-aggregated prefix: 1 atomic per wave. Prefix is node-ordered
        // within each 64-node chunk -> 16-aligned groups own contiguous
        // wsort ranges (node_score relies on this).
        int pre = c;
#pragma unroll
        for (int d = 1; d < 64; d <<= 1) {
            const int v = __shfl_up(pre, d);
            if (lane >= d) pre += v;
        }
        const int total = __shfl(pre, 63);
        int base = 0;
        if (lane == 63) base = (int)atomicAdd(cursor, (unsigned int)total);
        base = __shfl(base, 63);

        if (n < N_NODES) off[n] = base + pre - c;  // exclusive prefix
    } else {
        // ---- node_u role: thread = (node, class-PAIR), A staged in LDS ----
        for (int i = t; i < 226 * 5; i += 256) {
            const int row = i / 5, cp = i - row * 5;
            lA[i] = *reinterpret_cast<const float2*>(A + (size_t)row * 16 + 2 * cp);
        }
        __syncthreads();

        const int tid = (blockIdx.x - NB_ALLOC) * 256 + t;
        if (tid >= N_NODES * 5) return;
        const int n = tid / 5;
        const int cp = tid - n * 5;

        float vs0 = 0.f, vs1 = 0.f, v00 = 0.f, v01 = 0.f, v10 = 0.f, v11 = 0.f;

        const float4* Ov = reinterpret_cast<const float4*>(O + (size_t)n * 64);
#pragma unroll
        for (int kc = 0; kc < 16; ++kc) {
            const float4 o4 = Ov[kc];
#pragma unroll
            for (int j = 0; j < 4; ++j) {
                const float ov = (j == 0) ? o4.x : (j == 1) ? o4.y : (j == 2) ? o4.z : o4.w;
                const int k = kc * 4 + j;
                const float2 aO = lA[k * 5 + cp];
                const float2 aS = lA[(80 + k) * 5 + cp];
                const float2 aD = lA[(160 + k) * 5 + cp];
                v00 = fmaf(ov, aO.x, v00); v01 = fmaf(ov, aO.y, v01);
                vs0 = fmaf(ov, aS.x, vs0); vs1 = fmaf(ov, aS.y, vs1);
                v10 = fmaf(ov, aD.x, v10); v11 = fmaf(ov, aD.y, v11);
            }
        }
        const float4* Xv = reinterpret_cast<const float4*>(X + (size_t)n * 16);
#pragma unroll
        for (int kc = 0; kc < 4; ++kc) {
            const float4 x4 = Xv[kc];
#pragma unroll
            for (int j = 0; j < 4; ++j) {
                const float xv = (j == 0) ? x4.x : (j == 1) ? x4.y : (j == 2) ? x4.z : x4.w;
                const int k = 64 + kc * 4 + j;
                const float2 aX = lA[k * 5 + cp];
                v00 = fmaf(xv, aX.x, v00); v01 = fmaf(xv, aX.y, v01);
            }
        }

        const float2 c0 = lA[224 * 5 + cp];
        const float2 c1 = lA[225 * 5 + cp];
        *reinterpret_cast<float2*>(us + (size_t)n * 12 + 2 * cp) = make_float2(vs0, vs1);
        *reinterpret_cast<float2*>(u01 + (size_t)n * 20 + 2 * cp) =
            make_float2(v00 + c1.x, v01 + c1.y);
        *reinterpret_cast<float2*>(u01 + (size_t)n * 20 + 10 + 2 * cp) =
            make_float2(v10 + c0.x, v11 + c0.y);
    }
}

// ---------------------------------------------------------------------------
// Per-edge w_e = u_s[s_e] + R_a[e]@A_R -> bf16-packed, written directly to
// receiver-sorted slot pos = off[r] + goff[g(e)][r] + rank8[e]. No atomic.
// g(e) = (e>>10)&7: count block bt owned edges [bt*1024,(bt+1)*1024), g=bt&7.
// ---------------------------------------------------------------------------
__global__ __launch_bounds__(256) void edge_w_kernel(
    const float* __restrict__ R_a,
    const int* __restrict__ senders, const int* __restrict__ receivers,
    const unsigned char* __restrict__ rank8, const int* __restrict__ off,
    const int* __restrict__ goff,
    const float* __restrict__ us, const float* __restrict__ A,
    unsigned int* __restrict__ wsort)   // [E][5] dwords, receiver-sorted
{
    const int e = blockIdx.x * blockDim.x + threadIdx.x;
    if (e >= N_EDGES) return;
    const int s = senders[e];
    const int r = receivers[e];
    const int g = (e >> 10) & 7;
    const int pos = off[r] + goff[(size_t)g * N_NODES + r] + (int)rank8[e];

    // u_s[s]: 48 B gather from L2-resident 2.4 MB table
    const float4* U = reinterpret_cast<const float4*>(us + (size_t)s * 12);
    const float4 ua = U[0];
    const float4 ub = U[1];
    const float4 uc = U[2];
    float a[10] = {ua.x, ua.y, ua.z, ua.w, ub.x, ub.y, ub.z, ub.w, uc.x, uc.y};

    // R_a[e] @ A_R (A rows 144..159) — R_a streamed coalesced
    const float4* Rv = reinterpret_cast<const float4*>(R_a + (size_t)e * 16);
#pragma unroll
    for (int kc = 0; kc < 4; ++kc) {
        const float4 b4 = Rv[kc];
        const float* A0 = A + (size_t)(144 + kc * 4) * 16;
#pragma unroll
        for (int c = 0; c < 10; ++c) a[c] = fmaf(b4.x, A0[c], a[c]);
#pragma unroll
        for (int c = 0; c < 10; ++c) a[c] = fmaf(b4.y, A0[16 + c], a[c]);
#pragma unroll
        for (int c = 0; c < 10; ++c) a[c] = fmaf(b4.z, A0[32 + c], a[c]);
#pragma unroll
        for (int c = 0; c < 10; ++c) a[c] = fmaf(b4.w, A0[48 + c], a[c]);
    }

    unsigned int* wp = wsort + (size_t)pos * 5;
    wp[0] = f32_to_bf16_rne(a[0]) | (f32_to_bf16_rne(a[1]) << 16);
    wp[1] = f32_to_bf16_rne(a[2]) | (f32_to_bf16_rne(a[3]) << 16);
    wp[2] = f32_to_bf16_rne(a[4]) | (f32_to_bf16_rne(a[5]) << 16);
    wp[3] = f32_to_bf16_rne(a[6]) | (f32_to_bf16_rne(a[7]) << 16);
    wp[4] = f32_to_bf16_rne(a[8]) | (f32_to_bf16_rne(a[9]) << 16);
}

// ---------------------------------------------------------------------------
// Node scores (r15): block = 16 aligned nodes = one CONTIGUOUS wsort range.
// Stream range into LDS coalesced (512-record chunks), reduce from LDS.
// ---------------------------------------------------------------------------
#define CH_REC 512   // records per LDS chunk (2560 dwords = 10,240 B)

__global__ __launch_bounds__(256) void node_score_kernel(
    const float* __restrict__ u01,
    const int* __restrict__ off, const int* __restrict__ count,
    const unsigned int* __restrict__ w,   // [E][5] dwords, receiver-sorted
    float* __restrict__ out)
{
    __shared__ unsigned int lw[CH_REC * 5];
    const int t = threadIdx.x;
    const int n0 = blockIdx.x * 16;        // 16 | 64 -> block range contiguous
    const int g = t >> 4;                  // group 0..15 -> node n0+g
    const int lane = t & 15;
    const int n = n0 + g;                  // N_NODES % 16 == 0

    const int beg16 = off[n0];
    const int end16 = off[n0 + 15] + count[n0 + 15];

    const int beg = off[n];
    const int cnt = count[n];
    const int dge = cnt;

    const int cc = (lane < 10) ? lane : 0;
    const int half = cc >> 1;
    const int sh = (cc & 1) * 16;

    float sc = u01[(size_t)n * 20 + cc] + (float)dge * u01[(size_t)n * 20 + 10 + cc];

    for (int c0 = beg16; c0 < end16; c0 += CH_REC) {
        const int nrec = min(CH_REC, end16 - c0);
        const int ndw = nrec * 5;
        __syncthreads();
        for (int i = t; i < ndw; i += 256)
            lw[i] = w[(size_t)c0 * 5 + i];
        __syncthreads();

        const int j0 = max(beg, c0);
        const int j1 = min(beg + cnt, c0 + nrec);
        for (int j = j0; j < j1; ++j) {
            const unsigned int v = lw[(j - c0) * 5 + half];
            sc += __uint_as_float((v >> sh) << 16);
        }
    }

    // softmax over the 10 active lanes of this 16-lane group
    float m = (lane < 10) ? sc : -3.0e38f;
#pragma unroll
    for (int d = 1; d < 16; d <<= 1) m = fmaxf(m, __shfl_xor(m, d, 16));
    const float ex = (lane < 10) ? __expf(sc - m) : 0.f;
    float sum = ex;
#pragma unroll
    for (int d = 1; d < 16; d <<= 1) sum += __shfl_xor(sum, d, 16);
    if (lane < 10) out[(size_t)n * 10 + lane] = ex / sum;
}

extern "C" void kernel_launch(void* const* d_in, const int* in_sizes, int n_in,
                              void* d_out, int out_size, void* d_ws, size_t ws_size,
                              hipStream_t stream)
{
    const float* O    = (const float*)d_in[0];
    const float* X    = (const float*)d_in[1];
    const float* R_a  = (const float*)d_in[2];
    const int* senders   = (const int*)d_in[3];
    const int* receivers = (const int*)d_in[4];
    const float* W_r  = (const float*)d_in[5];
    const float* b_r  = (const float*)d_in[6];
    const float* W_o  = (const float*)d_in[7];
    const float* b_o  = (const float*)d_in[8];
    const float* W_s  = (const float*)d_in[9];
    const float* b_s  = (const float*)d_in[10];
    float* out = (float*)d_out;
    char* ws = (char*)d_ws;

    float* A      = (float*)(ws + WS_A);
    int* count    = (int*)(ws + WS_COUNT);
    int* off      = (int*)(ws + WS_OFF);
    unsigned char* rank8 = (unsigned char*)(ws + WS_RANK8);
    unsigned int* cursor = (unsigned int*)(ws + WS_CURSOR);
    int* cpriv    = (int*)(ws + WS_CPRIV);
    float* us     = (float*)(ws + WS_US);
    float* u01    = (float*)(ws + WS_U01);
    unsigned int* wsort = (unsigned int*)(ws + WS_WSORT);

    // zero cursor + private histograms (contiguous) in one memset
    hipMemsetAsync(ws + WS_CURSOR, 0, (size_t)(64 + 8 * N_NODES * 4), stream);

    fused_prep_kernel<<<NB_PRE + NB_CR, 256, 0, stream>>>(
        W_r, b_r, W_o, b_o, W_s, b_s, receivers, A, cpriv, rank8);

    fused_mid_kernel<<<NB_ALLOC + NB_NU, 256, 0, stream>>>(
        O, X, A, cpriv, count, cursor, off, us, u01);

    edge_w_kernel<<<(N_EDGES + 255) / 256, 256, 0, stream>>>(
        R_a, senders, receivers, rank8, off, cpriv, us, A, wsort);

    node_score_kernel<<<N_NODES / 16, 256, 0, stream>>>(
        u01, off, count, wsort, out);
}

// Round 20
// 116.837 us; speedup vs baseline: 1.0212x; 1.0212x over previous
//
#include <hip/hip_runtime.h>

#define N_NODES 50000
#define N_EDGES 800000
// D_S=64, D_R=16, D_E=64, D_X=16, D_P=64, NUM_CLASSES=10
// W_r: [144,64]; W_o: [144,64]; W_s: [64,10] (all row-major)
//
// Linear refactor: scores[n] = u0[n] + deg_n*u1[n] + sum_{e->n} w_e
//   w_e  = u_s[s_e] + R_a[e]@A_R          (computed in EDGE order, streamed)
//   u_s[n] = O[n]@A_S ; u0[n] = O[n]@A_O + X[n]@A_X + c1 ; u1[n] = O[n]@A_dO + c0
// with Wc = W_o@W_s [144,10], Wc2 = Wc[80:144],
//   A_O = Wc[0:64], A_X = Wc[64:80], A_S = W_r[0:64]@Wc2,
//   A_R = W_r[128:144]@Wc2, A_dO = W_r[64:128]@Wc2,
//   c0 = b_r@Wc2, c1 = b_o@W_s + b_s.
//
// FINAL STRUCTURE (r16). Measured walls that define the floor:
//   - histogram/rank: 800K unique-key device atomics ~50 us (~15-18 G/s;
//     r0/r16/r18; r19 XCD-privatization = null -> fabric-side intrinsic)
//   - record scatter: 800K random-line stores ~52 us (payload-invariant
//     r8/r9/r11; nt worse r14; bins worse r13; ILP-invariant r12;
//     fused atomic-claim variant 87 us r5 -> walls don't overlap)
//   - serial dependence (CSR build -> fill) => ~100 us permutation floor
//   - software grid barriers (r17) cost MORE than dispatch boundaries on
//     8 non-coherent XCD L2s (full wb/inv per barrier)
// Everything else: r10 LDS-table node_u, r15 LDS-chunk node_score, r16
// DAG-pair fusion (7->5 dispatches, ~4.5 us/boundary).
//
// A-table layout in ws: [226][16] f32 (cols 10..15 zeroed):
//   rows 0..63 A_O | 64..79 A_X | 80..143 A_S | 144..159 A_R |
//   160..223 A_dO | 224 c0 | 225 c1

// ---------------------------------------------------------------------------
// Workspace layout (bytes) — end = 26,019,328 < 26,414,400 (proven in r3)
// ---------------------------------------------------------------------------
#define WS_A       ((size_t)0)          // 14,464 B
#define WS_COUNT   ((size_t)16384)      // 50000 i32 = 200,000 B
#define WS_CURSOR  ((size_t)216384)     // 1 u32 (zeroed with count memset)
#define WS_OFF     ((size_t)217088)     // 50000 i32 = 200,000 B
#define WS_RANK    ((size_t)417792)     // 800000 i32 = 3,200,000 B
#define WS_US      ((size_t)3618816)    // 50000*12 f32 = 2,400,000 B
#define WS_U01     ((size_t)6019072)    // 50000*20 f32 = 4,000,000 B
#define WS_WSORT   ((size_t)10019328)   // 800000*5 u32 = 16,000,000 B

#define NB_PRE   10                     // precompute_A blocks
#define NB_CR    ((N_EDGES / 4 + 255) / 256)        // 782 count_rank blocks
#define NB_ALLOC ((N_NODES + 255) / 256)            // 196 alloc blocks
#define NB_NU    ((N_NODES * 5 + 255) / 256)        // 977 node_u blocks

__device__ __forceinline__ unsigned int f32_to_bf16_rne(float f) {
    unsigned int x = __float_as_uint(f);
    return (x + 0x7fffu + ((x >> 16) & 1u)) >> 16;
}

// ---------------------------------------------------------------------------
// Fused K1: blocks [0,NB_PRE) precompute A; blocks [NB_PRE,..) count+rank.
// Independent outputs (A vs count/rank) — safe to co-dispatch.
// ---------------------------------------------------------------------------
__global__ __launch_bounds__(256) void fused_prep_kernel(
    const float* __restrict__ W_r, const float* __restrict__ b_r,
    const float* __restrict__ W_o, const float* __restrict__ b_o,
    const float* __restrict__ W_s, const float* __restrict__ b_s,
    const int* __restrict__ receivers,
    float* __restrict__ A, int* __restrict__ count, int* __restrict__ rank)
{
    __shared__ float Wc2[640];  // used by precompute role only
    const int t = threadIdx.x;

    if (blockIdx.x < NB_PRE) {
        // ---- precompute_A role (grid-stride over NB_PRE blocks) ----
        for (int idx = t; idx < 640; idx += 256) {
            const int row = 80 + idx / 10, c = idx % 10;
            float acc = 0.f;
            for (int j = 0; j < 64; ++j)
                acc = fmaf(W_o[row * 64 + j], W_s[j * 10 + c], acc);
            Wc2[idx] = acc;
        }
        __syncthreads();

        for (int g = blockIdx.x * 256 + t; g < 3616; g += NB_PRE * 256) {
            if (g < 1356) {
                const int row = g / 6, c = 10 + g % 6;
                A[row * 16 + c] = 0.f;
            } else if (g < 2156) {
                const int i = g - 1356, row = i / 10, c = i % 10;
                float acc = 0.f;
                for (int j = 0; j < 64; ++j)
                    acc = fmaf(W_o[row * 64 + j], W_s[j * 10 + c], acc);
                A[row * 16 + c] = acc;
            } else if (g < 3596) {
                const int i = g - 2156, k = i / 10, c = i % 10;
                const int wrow = (k < 64) ? k : (k < 80 ? 128 + (k - 64) : 64 + (k - 80));
                const int arow = (k < 64) ? 80 + k : (k < 80 ? 144 + (k - 64) : 160 + (k - 80));
                const float* src = W_r + (size_t)wrow * 64;
                float acc = 0.f;
                for (int m = 0; m < 64; ++m)
                    acc = fmaf(src[m], Wc2[m * 10 + c], acc);
                A[arow * 16 + c] = acc;
            } else if (g < 3606) {
                const int c = g - 3596;
                float acc = 0.f;
                for (int m = 0; m < 64; ++m)
                    acc = fmaf(b_r[m], Wc2[m * 10 + c], acc);
                A[224 * 16 + c] = acc;
            } else {
                const int c = g - 3606;
                float acc = b_s[c];
                for (int j = 0; j < 64; ++j)
                    acc = fmaf(b_o[j], W_s[j * 10 + c], acc);
                A[225 * 16 + c] = acc;
            }
        }
    } else {
        // ---- count_rank role: atomic's return value IS the rank ----
        const int bt = (blockIdx.x - NB_PRE) * 256 + t;
        if (bt * 4 >= N_EDGES) return;
        const int4 r4 = reinterpret_cast<const int4*>(receivers)[bt];
        int4 k4;
        k4.x = atomicAdd(count + r4.x, 1);
        k4.y = atomicAdd(count + r4.y, 1);
        k4.z = atomicAdd(count + r4.z, 1);
        k4.w = atomicAdd(count + r4.w, 1);
        reinterpret_cast<int4*>(rank)[bt] = k4;
    }
}

// ---------------------------------------------------------------------------
// Fused K2: blocks [0,NB_ALLOC) segment-alloc; blocks [NB_ALLOC,..) node_u.
// alloc needs count (K1); node_u needs A (K1). Disjoint outputs.
// ---------------------------------------------------------------------------
__global__ __launch_bounds__(256) void fused_mid_kernel(
    const float* __restrict__ O, const float* __restrict__ X,
    const float* __restrict__ A,
    const int* __restrict__ count, unsigned int* __restrict__ cursor,
    int* __restrict__ off,
    float* __restrict__ us, float* __restrict__ u01)
{
    __shared__ float2 lA[226 * 5];  // used by node_u role only
    const int t = threadIdx.x;

    if (blockIdx.x < NB_ALLOC) {
        // ---- alloc role: wave-aggregated prefix, 1 atomic per wave.
        // Prefix is node-ordered within each 64-node wave chunk -> any
        // 16-aligned node group owns a contiguous wsort range (node_score).
        const int n = blockIdx.x * 256 + t;
        const int lane = t & 63;
        const int c = (n < N_NODES) ? count[n] : 0;

        int pre = c;
#pragma unroll
        for (int d = 1; d < 64; d <<= 1) {
            const int v = __shfl_up(pre, d);
            if (lane >= d) pre += v;
        }
        const int total = __shfl(pre, 63);
        int base = 0;
        if (lane == 63) base = (int)atomicAdd(cursor, (unsigned int)total);
        base = __shfl(base, 63);

        if (n < N_NODES) off[n] = base + pre - c;  // exclusive prefix
    } else {
        // ---- node_u role: thread = (node, class-PAIR), A staged in LDS ----
        for (int i = t; i < 226 * 5; i += 256) {
            const int row = i / 5, cp = i - row * 5;
            lA[i] = *reinterpret_cast<const float2*>(A + (size_t)row * 16 + 2 * cp);
        }
        __syncthreads();

        const int tid = (blockIdx.x - NB_ALLOC) * 256 + t;
        if (tid >= N_NODES * 5) return;
        const int n = tid / 5;
        const int cp = tid - n * 5;

        float vs0 = 0.f, vs1 = 0.f, v00 = 0.f, v01 = 0.f, v10 = 0.f, v11 = 0.f;

        const float4* Ov = reinterpret_cast<const float4*>(O + (size_t)n * 64);
#pragma unroll
        for (int kc = 0; kc < 16; ++kc) {
            const float4 o4 = Ov[kc];
#pragma unroll
            for (int j = 0; j < 4; ++j) {
                const float ov = (j == 0) ? o4.x : (j == 1) ? o4.y : (j == 2) ? o4.z : o4.w;
                const int k = kc * 4 + j;
                const float2 aO = lA[k * 5 + cp];
                const float2 aS = lA[(80 + k) * 5 + cp];
                const float2 aD = lA[(160 + k) * 5 + cp];
                v00 = fmaf(ov, aO.x, v00); v01 = fmaf(ov, aO.y, v01);
                vs0 = fmaf(ov, aS.x, vs0); vs1 = fmaf(ov, aS.y, vs1);
                v10 = fmaf(ov, aD.x, v10); v11 = fmaf(ov, aD.y, v11);
            }
        }
        const float4* Xv = reinterpret_cast<const float4*>(X + (size_t)n * 16);
#pragma unroll
        for (int kc = 0; kc < 4; ++kc) {
            const float4 x4 = Xv[kc];
#pragma unroll
            for (int j = 0; j < 4; ++j) {
                const float xv = (j == 0) ? x4.x : (j == 1) ? x4.y : (j == 2) ? x4.z : x4.w;
                const int k = 64 + kc * 4 + j;
                const float2 aX = lA[k * 5 + cp];
                v00 = fmaf(xv, aX.x, v00); v01 = fmaf(xv, aX.y, v01);
            }
        }

        const float2 c0 = lA[224 * 5 + cp];
        const float2 c1 = lA[225 * 5 + cp];
        *reinterpret_cast<float2*>(us + (size_t)n * 12 + 2 * cp) = make_float2(vs0, vs1);
        *reinterpret_cast<float2*>(u01 + (size_t)n * 20 + 2 * cp) =
            make_float2(v00 + c1.x, v01 + c1.y);
        *reinterpret_cast<float2*>(u01 + (size_t)n * 20 + 10 + 2 * cp) =
            make_float2(v10 + c0.x, v11 + c0.y);
    }
}

// ---------------------------------------------------------------------------
// Per-edge w_e = u_s[s_e] + R_a[e]@A_R -> bf16-packed, written directly to
// receiver-sorted slot pos = off[r] + rank[e]. No atomic. Plain stores.
// ---------------------------------------------------------------------------
__global__ __launch_bounds__(256) void edge_w_kernel(
    const float* __restrict__ R_a,
    const int* __restrict__ senders, const int* __restrict__ receivers,
    const int* __restrict__ rank, const int* __restrict__ off,
    const float* __restrict__ us, const float* __restrict__ A,
    unsigned int* __restrict__ wsort)   // [E][5] dwords, receiver-sorted
{
    const int e = blockIdx.x * blockDim.x + threadIdx.x;
    if (e >= N_EDGES) return;
    const int s = senders[e];
    const int r = receivers[e];
    const int pos = off[r] + rank[e];   // plain loads — no atomic

    // u_s[s]: 48 B gather from L2-resident 2.4 MB table
    const float4* U = reinterpret_cast<const float4*>(us + (size_t)s * 12);
    const float4 ua = U[0];
    const float4 ub = U[1];
    const float4 uc = U[2];
    float a[10] = {ua.x, ua.y, ua.z, ua.w, ub.x, ub.y, ub.z, ub.w, uc.x, uc.y};

    // R_a[e] @ A_R (A rows 144..159) — R_a streamed coalesced
    const float4* Rv = reinterpret_cast<const float4*>(R_a + (size_t)e * 16);
#pragma unroll
    for (int kc = 0; kc < 4; ++kc) {
        const float4 b4 = Rv[kc];
        const float* A0 = A + (size_t)(144 + kc * 4) * 16;
#pragma unroll
        for (int c = 0; c < 10; ++c) a[c] = fmaf(b4.x, A0[c], a[c]);
#pragma unroll
        for (int c = 0; c < 10; ++c) a[c] = fmaf(b4.y, A0[16 + c], a[c]);
#pragma unroll
        for (int c = 0; c < 10; ++c) a[c] = fmaf(b4.z, A0[32 + c], a[c]);
#pragma unroll
        for (int c = 0; c < 10; ++c) a[c] = fmaf(b4.w, A0[48 + c], a[c]);
    }

    unsigned int* wp = wsort + (size_t)pos * 5;
    wp[0] = f32_to_bf16_rne(a[0]) | (f32_to_bf16_rne(a[1]) << 16);
    wp[1] = f32_to_bf16_rne(a[2]) | (f32_to_bf16_rne(a[3]) << 16);
    wp[2] = f32_to_bf16_rne(a[4]) | (f32_to_bf16_rne(a[5]) << 16);
    wp[3] = f32_to_bf16_rne(a[6]) | (f32_to_bf16_rne(a[7]) << 16);
    wp[4] = f32_to_bf16_rne(a[8]) | (f32_to_bf16_rne(a[9]) << 16);
}

// ---------------------------------------------------------------------------
// Node scores (r15): block = 16 aligned nodes = one CONTIGUOUS wsort range.
// Stream range into LDS coalesced (512-record chunks), reduce from LDS.
// ---------------------------------------------------------------------------
#define CH_REC 512   // records per LDS chunk (2560 dwords = 10,240 B)

__global__ __launch_bounds__(256) void node_score_kernel(
    const float* __restrict__ u01,
    const int* __restrict__ off, const int* __restrict__ count,
    const unsigned int* __restrict__ w,   // [E][5] dwords, receiver-sorted
    float* __restrict__ out)
{
    __shared__ unsigned int lw[CH_REC * 5];
    const int t = threadIdx.x;
    const int n0 = blockIdx.x * 16;        // 16 | 64 -> block range contiguous
    const int g = t >> 4;                  // group 0..15 -> node n0+g
    const int lane = t & 15;
    const int n = n0 + g;                  // N_NODES % 16 == 0

    const int beg16 = off[n0];
    const int end16 = off[n0 + 15] + count[n0 + 15];

    const int beg = off[n];
    const int cnt = count[n];
    const int dge = cnt;

    const int cc = (lane < 10) ? lane : 0;
    const int half = cc >> 1;
    const int sh = (cc & 1) * 16;

    float sc = u01[(size_t)n * 20 + cc] + (float)dge * u01[(size_t)n * 20 + 10 + cc];

    for (int c0 = beg16; c0 < end16; c0 += CH_REC) {
        const int nrec = min(CH_REC, end16 - c0);
        const int ndw = nrec * 5;
        __syncthreads();
        for (int i = t; i < ndw; i += 256)
            lw[i] = w[(size_t)c0 * 5 + i];
        __syncthreads();

        const int j0 = max(beg, c0);
        const int j1 = min(beg + cnt, c0 + nrec);
        for (int j = j0; j < j1; ++j) {
            const unsigned int v = lw[(j - c0) * 5 + half];
            sc += __uint_as_float((v >> sh) << 16);
        }
    }

    // softmax over the 10 active lanes of this 16-lane group
    float m = (lane < 10) ? sc : -3.0e38f;
#pragma unroll
    for (int d = 1; d < 16; d <<= 1) m = fmaxf(m, __shfl_xor(m, d, 16));
    const float ex = (lane < 10) ? __expf(sc - m) : 0.f;
    float sum = ex;
#pragma unroll
    for (int d = 1; d < 16; d <<= 1) sum += __shfl_xor(sum, d, 16);
    if (lane < 10) out[(size_t)n * 10 + lane] = ex / sum;
}

extern "C" void kernel_launch(void* const* d_in, const int* in_sizes, int n_in,
                              void* d_out, int out_size, void* d_ws, size_t ws_size,
                              hipStream_t stream)
{
    const float* O    = (const float*)d_in[0];
    const float* X    = (const float*)d_in[1];
    const float* R_a  = (const float*)d_in[2];
    const int* senders   = (const int*)d_in[3];
    const int* receivers = (const int*)d_in[4];
    const float* W_r  = (const float*)d_in[5];
    const float* b_r  = (const float*)d_in[6];
    const float* W_o  = (const float*)d_in[7];
    const float* b_o  = (const float*)d_in[8];
    const float* W_s  = (const float*)d_in[9];
    const float* b_s  = (const float*)d_in[10];
    float* out = (float*)d_out;
    char* ws = (char*)d_ws;

    float* A      = (float*)(ws + WS_A);
    int* count    = (int*)(ws + WS_COUNT);
    unsigned int* cursor = (unsigned int*)(ws + WS_CURSOR);
    int* off      = (int*)(ws + WS_OFF);
    int* rank     = (int*)(ws + WS_RANK);
    float* us     = (float*)(ws + WS_US);
    float* u01    = (float*)(ws + WS_U01);
    unsigned int* wsort = (unsigned int*)(ws + WS_WSORT);

    // zero count histogram + cursor (adjacent) in one memset
    hipMemsetAsync(count, 0, (size_t)(200000 + 4 + 384), stream);

    fused_prep_kernel<<<NB_PRE + NB_CR, 256, 0, stream>>>(
        W_r, b_r, W_o, b_o, W_s, b_s, receivers, A, count, rank);

    fused_mid_kernel<<<NB_ALLOC + NB_NU, 256, 0, stream>>>(
        O, X, A, count, cursor, off, us, u01);

    edge_w_kernel<<<(N_EDGES + 255) / 256, 256, 0, stream>>>(
        R_a, senders, receivers, rank, off, us, A, wsort);

    node_score_kernel<<<N_NODES / 16, 256, 0, stream>>>(
        u01, off, count, wsort, out);
}